// Round 3
// baseline (91.190 us; speedup 1.0000x reference)
//
#include <hip/hip_runtime.h>
#include <math.h>

#define Bq 512
#define Dq 256
#define RPB 16              // rows per prep block
#define PBLK (Bq / RPB)     // 32 prep blocks

__device__ __forceinline__ float waveReduceSum(float v) {
    #pragma unroll
    for (int off = 32; off > 0; off >>= 1)
        v += __shfl_xor(v, off, 64);
    return v;
}

// Kernel 1: normalize rows, emit row-major A1=a, A2=a^2, C0=1+a^3 and
// transposed fT[k*Bq + i] = a, with LDS-transposed (mostly coalesced) stores.
// Also zeroes the accumulator + ticket counter used by pair_kernel.
__global__ __launch_bounds__(256) void prep_kernel(
        const float* __restrict__ feat,
        float* __restrict__ fT, float* __restrict__ A1,
        float* __restrict__ A2, float* __restrict__ C0,
        float* __restrict__ acc, unsigned int* __restrict__ cnt) {
    const int t = threadIdx.x;
    const int r0 = blockIdx.x * RPB;
    __shared__ float sm[RPB][Dq + 1];      // stride 257 -> bank-conflict-free
    __shared__ float wpart[RPB][4];
    __shared__ float sinv[RPB];

    float x[RPB];
    #pragma unroll
    for (int r = 0; r < RPB; ++r) x[r] = feat[(r0 + r) * Dq + t];

    const int wid = t >> 6, lane = t & 63;
    #pragma unroll
    for (int r = 0; r < RPB; ++r) {
        float ss = waveReduceSum(x[r] * x[r]);
        if (lane == 0) wpart[r][wid] = ss;
    }
    __syncthreads();
    if (t < RPB) {
        float tot = wpart[t][0] + wpart[t][1] + wpart[t][2] + wpart[t][3];
        sinv[t] = 1.0f / fmaxf(sqrtf(tot), 1e-12f);
    }
    __syncthreads();

    #pragma unroll
    for (int r = 0; r < RPB; ++r) {
        float a  = x[r] * sinv[r];
        float a2 = a * a;
        float c0 = 1.0f + a2 * a;
        A1[(r0 + r) * Dq + t] = a;     // coalesced
        A2[(r0 + r) * Dq + t] = a2;
        C0[(r0 + r) * Dq + t] = c0;
        sm[r][t] = a;
    }
    __syncthreads();

    // fT[k*Bq + (r0+rr)] = sm[rr][k]; lanes 0..15 cover 16 consecutive i's
    // at one k -> 64B segments (4 per wave-store) instead of 64-way scatter.
    const int rr = t & 15, kb = t >> 4;    // kb in 0..15
    #pragma unroll
    for (int p = 0; p < 16; ++p) {
        int k = p * 16 + kb;
        fT[k * Bq + r0 + rr] = sm[rr][k];
    }

    if (blockIdx.x == 0 && t == 0) { *acc = 0.0f; *cnt = 0u; }
}

// Kernel 2: block per i (256 thr), thread owns j0=2t, j0+1.
//   g  = c0*b          -> du += a*g,  nu += g*g      (raw_self path)
//   wb = b + a2*b*b    -> dv += a*wb, nv += wb*wb    (raw_other path)
// t_i = S_i/B - log(V_i) atomically accumulated; last block writes d_out.
__global__ __launch_bounds__(256) void pair_kernel(
        const float* __restrict__ fT,
        const float* __restrict__ A1, const float* __restrict__ A2,
        const float* __restrict__ C0,
        float* __restrict__ acc, unsigned int* __restrict__ cnt,
        float* __restrict__ out) {
    const int i = blockIdx.x;
    const int t = threadIdx.x;
    const int j0 = 2 * t;

    __shared__ __align__(16) float s_a[Dq];
    __shared__ __align__(16) float s_a2[Dq];
    __shared__ __align__(16) float s_c0[Dq];
    s_a[t]  = A1[i * Dq + t];
    s_a2[t] = A2[i * Dq + t];
    s_c0[t] = C0[i * Dq + t];
    __syncthreads();

    const float4* __restrict__ va  = (const float4*)s_a;
    const float4* __restrict__ va2 = (const float4*)s_a2;
    const float4* __restrict__ vc0 = (const float4*)s_c0;
    const float* __restrict__ pb = fT + j0;

    float du0 = 0.f, nu0 = 0.f, dv0 = 0.f, nv0 = 0.f;
    float du1 = 0.f, nu1 = 0.f, dv1 = 0.f, nv1 = 0.f;

    #pragma unroll 4
    for (int k4 = 0; k4 < Dq / 4; ++k4) {
        float4 a4  = va[k4];
        float4 q4  = va2[k4];
        float4 c4  = vc0[k4];
        const float aa[4] = {a4.x, a4.y, a4.z, a4.w};
        const float qq[4] = {q4.x, q4.y, q4.z, q4.w};
        const float cc[4] = {c4.x, c4.y, c4.z, c4.w};
        #pragma unroll
        for (int kk = 0; kk < 4; ++kk) {
            int k = k4 * 4 + kk;
            float2 bv = *(const float2*)(pb + k * Bq);   // coalesced 8B/lane
            {
                float b  = bv.x;
                float bb = b * b;
                float g  = cc[kk] * b;
                float wb = fmaf(qq[kk], bb, b);
                du0 = fmaf(aa[kk], g,  du0);
                nu0 = fmaf(g,      g,  nu0);
                dv0 = fmaf(aa[kk], wb, dv0);
                nv0 = fmaf(wb,     wb, nv0);
            }
            {
                float b  = bv.y;
                float bb = b * b;
                float g  = cc[kk] * b;
                float wb = fmaf(qq[kk], bb, b);
                du1 = fmaf(aa[kk], g,  du1);
                nu1 = fmaf(g,      g,  nu1);
                dv1 = fmaf(aa[kk], wb, dv1);
                nv1 = fmaf(wb,     wb, nv1);
            }
        }
    }

    const float Tinv = 1.0f / 0.07f;
    float raw_s0 = du0 / fmaxf(sqrtf(nu0), 1e-12f) * Tinv;
    float raw_o0 = dv0 / fmaxf(sqrtf(nv0), 1e-12f) * Tinv;
    float raw_s1 = du1 / fmaxf(sqrtf(nu1), 1e-12f) * Tinv;
    float raw_o1 = dv1 / fmaxf(sqrtf(nv1), 1e-12f) * Tinv;

    float sS = raw_s0 + raw_s1;                       // diagonal included in S
    float sV = 0.f;
    if (j0 != i)     sV += expf(raw_s0) + 3.0f * expf(raw_o0);
    if (j0 + 1 != i) sV += expf(raw_s1) + 3.0f * expf(raw_o1);

    sS = waveReduceSum(sS);
    sV = waveReduceSum(sV);
    __shared__ float redS[4], redV[4];
    const int wid = t >> 6, lane = t & 63;
    if (lane == 0) { redS[wid] = sS; redV[wid] = sV; }
    __syncthreads();
    if (t == 0) {
        float S = redS[0] + redS[1] + redS[2] + redS[3];
        float V = redV[0] + redV[1] + redV[2] + redV[3];
        float ti = S * (1.0f / Bq) - logf(V);
        atomicAdd(acc, ti);
        __threadfence();
        unsigned int old = atomicAdd(cnt, 1u);
        if (old == Bq - 1) {
            float tot = atomicAdd(acc, 0.0f);         // atomic read, device scope
            out[0] = -tot / (float)Bq;
        }
    }
}

extern "C" void kernel_launch(void* const* d_in, const int* in_sizes, int n_in,
                              void* d_out, int out_size, void* d_ws, size_t ws_size,
                              hipStream_t stream) {
    const float* feat = (const float*)d_in[0];
    float* ws = (float*)d_ws;
    float* fT = ws;                       // Dq*Bq
    float* A1 = fT + (size_t)Bq * Dq;     // Bq*Dq
    float* A2 = A1 + (size_t)Bq * Dq;
    float* C0 = A2 + (size_t)Bq * Dq;
    float* acc = C0 + (size_t)Bq * Dq;    // 1
    unsigned int* cnt = (unsigned int*)(acc + 1);

    prep_kernel<<<PBLK, 256, 0, stream>>>(feat, fT, A1, A2, C0, acc, cnt);
    pair_kernel<<<Bq, 256, 0, stream>>>(fT, A1, A2, C0, acc, cnt, (float*)d_out);
}

// Round 4
// 79.180 us; speedup vs baseline: 1.1517x; 1.1517x over previous
//
#include <hip/hip_runtime.h>
#include <math.h>

#define Bq 512
#define Dq 256

__device__ __forceinline__ float waveReduceSum(float v) {
    #pragma unroll
    for (int off = 32; off > 0; off >>= 1)
        v += __shfl_xor(v, off, 64);
    return v;
}

// Kernel 1: per-row L2 normalize (block per row, R2 structure that measured 77us).
// Emits row-major A1=a, A2=a^2, C0=1+a^3 and transposed fT[k*Bq+i]=a.
__global__ __launch_bounds__(256) void prep_kernel(
        const float* __restrict__ feat,
        float* __restrict__ fT, float* __restrict__ A1,
        float* __restrict__ A2, float* __restrict__ C0) {
    int i = blockIdx.x;
    int k = threadIdx.x;
    float x = feat[i * Dq + k];
    float ss = waveReduceSum(x * x);
    __shared__ float wsum[4];
    int wid = threadIdx.x >> 6, lane = threadIdx.x & 63;
    if (lane == 0) wsum[wid] = ss;
    __syncthreads();
    float tot = wsum[0] + wsum[1] + wsum[2] + wsum[3];
    float n = fmaxf(sqrtf(tot), 1e-12f);
    float a = x / n;
    float a2 = a * a;
    float c0 = 1.0f + a2 * a;
    fT[k * Bq + i] = a;            // strided scatter, small & pipelined
    A1[i * Dq + k] = a;            // coalesced
    A2[i * Dq + k] = a2;
    C0[i * Dq + k] = c0;
}

// Kernel 2: block per (i0, i0+1) pair of rows; 256 threads; thread owns j0=2t, j0+1.
// One fT float2 load per k feeds FOUR (i,j) pairs.
//   g  = c0*b         -> du += a*g,  nu += g*g     (raw_self path)
//   wb = b + a2*b*b   -> dv += a*wb, nv += wb*wb   (raw_other path)
// Writes Tv[i] = S_i/B - log(V_i) per i (no atomics).
__global__ __launch_bounds__(256) void pair_kernel(
        const float* __restrict__ fT,
        const float* __restrict__ A1, const float* __restrict__ A2,
        const float* __restrict__ C0,
        float* __restrict__ Tv) {
    const int i0 = blockIdx.x * 2;
    const int t = threadIdx.x;
    const int j0 = 2 * t;

    __shared__ __align__(16) float s_a[2][Dq];
    __shared__ __align__(16) float s_q[2][Dq];
    __shared__ __align__(16) float s_c[2][Dq];
    #pragma unroll
    for (int r = 0; r < 2; ++r) {
        s_a[r][t] = A1[(i0 + r) * Dq + t];
        s_q[r][t] = A2[(i0 + r) * Dq + t];
        s_c[r][t] = C0[(i0 + r) * Dq + t];
    }
    __syncthreads();

    float du[2][2] = {{0.f,0.f},{0.f,0.f}};
    float nu[2][2] = {{0.f,0.f},{0.f,0.f}};
    float dv[2][2] = {{0.f,0.f},{0.f,0.f}};
    float nv[2][2] = {{0.f,0.f},{0.f,0.f}};

    const float* __restrict__ pb = fT + j0;

    #pragma unroll 2
    for (int k4 = 0; k4 < Dq / 4; ++k4) {
        float4 a4[2], q4[2], c4[2];
        #pragma unroll
        for (int r = 0; r < 2; ++r) {
            a4[r] = ((const float4*)s_a[r])[k4];
            q4[r] = ((const float4*)s_q[r])[k4];
            c4[r] = ((const float4*)s_c[r])[k4];
        }
        #pragma unroll
        for (int kk = 0; kk < 4; ++kk) {
            const int k = k4 * 4 + kk;
            float2 bv = *(const float2*)(pb + k * Bq);   // coalesced 8B/lane
            const float aa[2] = { ((const float*)&a4[0])[kk], ((const float*)&a4[1])[kk] };
            const float qq[2] = { ((const float*)&q4[0])[kk], ((const float*)&q4[1])[kk] };
            const float cc[2] = { ((const float*)&c4[0])[kk], ((const float*)&c4[1])[kk] };
            const float bs[2] = { bv.x, bv.y };
            #pragma unroll
            for (int jj = 0; jj < 2; ++jj) {
                float b  = bs[jj];
                float bb = b * b;
                #pragma unroll
                for (int ii = 0; ii < 2; ++ii) {
                    float g  = cc[ii] * b;
                    float wb = fmaf(qq[ii], bb, b);
                    du[ii][jj] = fmaf(aa[ii], g,  du[ii][jj]);
                    nu[ii][jj] = fmaf(g,      g,  nu[ii][jj]);
                    dv[ii][jj] = fmaf(aa[ii], wb, dv[ii][jj]);
                    nv[ii][jj] = fmaf(wb,     wb, nv[ii][jj]);
                }
            }
        }
    }

    const float Tinv = 1.0f / 0.07f;
    __shared__ float redS[2][4], redV[2][4];
    const int wid = t >> 6, lane = t & 63;

    #pragma unroll
    for (int ii = 0; ii < 2; ++ii) {
        const int i = i0 + ii;
        float sS = 0.f, sV = 0.f;
        #pragma unroll
        for (int jj = 0; jj < 2; ++jj) {
            const int j = j0 + jj;
            float raw_s = du[ii][jj] / fmaxf(sqrtf(nu[ii][jj]), 1e-12f) * Tinv;
            float raw_o = dv[ii][jj] / fmaxf(sqrtf(nv[ii][jj]), 1e-12f) * Tinv;
            sS += raw_s;                               // diagonal included in S
            if (j != i) sV += expf(raw_s) + 3.0f * expf(raw_o);
        }
        sS = waveReduceSum(sS);
        sV = waveReduceSum(sV);
        if (lane == 0) { redS[ii][wid] = sS; redV[ii][wid] = sV; }
    }
    __syncthreads();
    if (t < 2) {
        float S = redS[t][0] + redS[t][1] + redS[t][2] + redS[t][3];
        float V = redV[t][0] + redV[t][1] + redV[t][2] + redV[t][3];
        Tv[i0 + t] = S * (1.0f / Bq) - logf(V);
    }
}

// Kernel 3: loss = -(1/B) * sum_i Tv[i]
__global__ __launch_bounds__(512) void final_kernel(
        const float* __restrict__ Tv, float* __restrict__ out) {
    int i = threadIdx.x;
    float t = waveReduceSum(Tv[i]);
    __shared__ float red[8];
    int wid = i >> 6, lane = i & 63;
    if (lane == 0) red[wid] = t;
    __syncthreads();
    if (i == 0) {
        float s = 0.f;
        #pragma unroll
        for (int w = 0; w < 8; ++w) s += red[w];
        out[0] = -s / (float)Bq;
    }
}

extern "C" void kernel_launch(void* const* d_in, const int* in_sizes, int n_in,
                              void* d_out, int out_size, void* d_ws, size_t ws_size,
                              hipStream_t stream) {
    const float* feat = (const float*)d_in[0];
    float* ws = (float*)d_ws;
    float* fT = ws;                       // Dq*Bq
    float* A1 = fT + (size_t)Bq * Dq;     // Bq*Dq
    float* A2 = A1 + (size_t)Bq * Dq;
    float* C0 = A2 + (size_t)Bq * Dq;
    float* Tv = C0 + (size_t)Bq * Dq;     // Bq

    prep_kernel<<<Bq, Dq, 0, stream>>>(feat, fT, A1, A2, C0);
    pair_kernel<<<Bq / 2, 256, 0, stream>>>(fT, A1, A2, C0, Tv);
    final_kernel<<<1, Bq, 0, stream>>>(Tv, (float*)d_out);
}

// Round 5
// 78.573 us; speedup vs baseline: 1.1606x; 1.0077x over previous
//
#include <hip/hip_runtime.h>
#include <math.h>

#define Bq 512
#define Dq 256
#define RPB 16              // rows per prep block
#define PBLK (Bq / RPB)     // 32 prep blocks

__device__ __forceinline__ float waveReduceSum(float v) {
    #pragma unroll
    for (int off = 32; off > 0; off >>= 1)
        v += __shfl_xor(v, off, 64);
    return v;
}

// Kernel 1: normalize rows, write ONLY transposed fT[k*Bq+i]=a with
// LDS-transposed (64B-segment) stores. 32 blocks x 256 thr, 16 rows/block.
__global__ __launch_bounds__(256) void prep_kernel(
        const float* __restrict__ feat, float* __restrict__ fT) {
    const int t = threadIdx.x;
    const int r0 = blockIdx.x * RPB;
    __shared__ float sm[RPB][Dq + 1];     // +1: bank-conflict-free transpose
    __shared__ float wpart[RPB][4];
    __shared__ float sinv[RPB];

    float x[RPB];
    #pragma unroll
    for (int r = 0; r < RPB; ++r) x[r] = feat[(r0 + r) * Dq + t];

    const int wid = t >> 6, lane = t & 63;
    #pragma unroll
    for (int r = 0; r < RPB; ++r) {
        float ss = waveReduceSum(x[r] * x[r]);
        if (lane == 0) wpart[r][wid] = ss;
    }
    __syncthreads();
    if (t < RPB) {
        float tot = wpart[t][0] + wpart[t][1] + wpart[t][2] + wpart[t][3];
        sinv[t] = 1.0f / fmaxf(sqrtf(tot), 1e-12f);
    }
    __syncthreads();
    #pragma unroll
    for (int r = 0; r < RPB; ++r) sm[r][t] = x[r] * sinv[r];
    __syncthreads();

    // lanes 0..15 -> 16 consecutive i at one k: 4x64B segments per wave-store
    const int rr = t & 15, kb = t >> 4;
    #pragma unroll
    for (int p = 0; p < 16; ++p) {
        int k = p * 16 + kb;
        fT[k * Bq + r0 + rr] = sm[rr][k];
    }
}

// Kernel 2: grid = 512 blocks = (i-pair p) x (j-half h). 256 threads,
// thread owns j = h*256 + t, rows i0 = 2p, i0+1. Coefs computed in-block
// from feat (no A1/A2/C0 round-trip). Writes per-(i,h) partial S, V.
//   g  = (1+a^3)*b     -> du += a*g,  nu += g*g     (raw_self path)
//   wb = b + a^2*b^2   -> dv += a*wb, nv += wb*wb   (raw_other path)
__global__ __launch_bounds__(256) void pair_kernel(
        const float* __restrict__ feat, const float* __restrict__ fT,
        float* __restrict__ Sp, float* __restrict__ Vp) {
    const int p = blockIdx.x >> 1;
    const int h = blockIdx.x & 1;
    const int i0 = p * 2;
    const int t = threadIdx.x;
    const int j = h * 256 + t;
    const int wid = t >> 6, lane = t & 63;

    __shared__ __align__(16) float s_a[2][Dq];
    __shared__ __align__(16) float s_q[2][Dq];
    __shared__ __align__(16) float s_c[2][Dq];
    __shared__ float wpart[2][4];

    float x0 = feat[i0 * Dq + t];
    float x1 = feat[(i0 + 1) * Dq + t];
    float ss0 = waveReduceSum(x0 * x0);
    float ss1 = waveReduceSum(x1 * x1);
    if (lane == 0) { wpart[0][wid] = ss0; wpart[1][wid] = ss1; }
    __syncthreads();
    float inv0 = 1.0f / fmaxf(sqrtf(wpart[0][0] + wpart[0][1] + wpart[0][2] + wpart[0][3]), 1e-12f);
    float inv1 = 1.0f / fmaxf(sqrtf(wpart[1][0] + wpart[1][1] + wpart[1][2] + wpart[1][3]), 1e-12f);
    {
        float a0 = x0 * inv0, a1 = x1 * inv1;
        s_a[0][t] = a0; s_q[0][t] = a0 * a0; s_c[0][t] = 1.0f + a0 * a0 * a0;
        s_a[1][t] = a1; s_q[1][t] = a1 * a1; s_c[1][t] = 1.0f + a1 * a1 * a1;
    }
    __syncthreads();

    float du0 = 0.f, nu0 = 0.f, dv0 = 0.f, nv0 = 0.f;
    float du1 = 0.f, nu1 = 0.f, dv1 = 0.f, nv1 = 0.f;
    const float* __restrict__ pb = fT + j;

    #pragma unroll 4
    for (int k4 = 0; k4 < Dq / 4; ++k4) {
        float4 A0 = ((const float4*)s_a[0])[k4];
        float4 Q0 = ((const float4*)s_q[0])[k4];
        float4 Cc0 = ((const float4*)s_c[0])[k4];
        float4 A1v = ((const float4*)s_a[1])[k4];
        float4 Q1 = ((const float4*)s_q[1])[k4];
        float4 Cc1 = ((const float4*)s_c[1])[k4];
        #pragma unroll
        for (int kk = 0; kk < 4; ++kk) {
            float b  = pb[(k4 * 4 + kk) * Bq];   // coalesced 4B/lane (256B/wave)
            float bb = b * b;
            {
                float a = ((const float*)&A0)[kk];
                float q = ((const float*)&Q0)[kk];
                float c = ((const float*)&Cc0)[kk];
                float g  = c * b;
                float wb = fmaf(q, bb, b);
                du0 = fmaf(a,  g,  du0);
                nu0 = fmaf(g,  g,  nu0);
                dv0 = fmaf(a,  wb, dv0);
                nv0 = fmaf(wb, wb, nv0);
            }
            {
                float a = ((const float*)&A1v)[kk];
                float q = ((const float*)&Q1)[kk];
                float c = ((const float*)&Cc1)[kk];
                float g  = c * b;
                float wb = fmaf(q, bb, b);
                du1 = fmaf(a,  g,  du1);
                nu1 = fmaf(g,  g,  nu1);
                dv1 = fmaf(a,  wb, dv1);
                nv1 = fmaf(wb, wb, nv1);
            }
        }
    }

    const float Tinv = 1.0f / 0.07f;
    float raw_s0 = du0 / fmaxf(sqrtf(nu0), 1e-12f) * Tinv;
    float raw_o0 = dv0 / fmaxf(sqrtf(nv0), 1e-12f) * Tinv;
    float raw_s1 = du1 / fmaxf(sqrtf(nu1), 1e-12f) * Tinv;
    float raw_o1 = dv1 / fmaxf(sqrtf(nv1), 1e-12f) * Tinv;

    float sS0 = raw_s0, sS1 = raw_s1;                 // diagonal included in S
    float sV0 = (j != i0)     ? expf(raw_s0) + 3.0f * expf(raw_o0) : 0.0f;
    float sV1 = (j != i0 + 1) ? expf(raw_s1) + 3.0f * expf(raw_o1) : 0.0f;

    sS0 = waveReduceSum(sS0); sV0 = waveReduceSum(sV0);
    sS1 = waveReduceSum(sS1); sV1 = waveReduceSum(sV1);
    __shared__ float redS[2][4], redV[2][4];
    if (lane == 0) {
        redS[0][wid] = sS0; redV[0][wid] = sV0;
        redS[1][wid] = sS1; redV[1][wid] = sV1;
    }
    __syncthreads();
    if (t < 2) {
        float S = redS[t][0] + redS[t][1] + redS[t][2] + redS[t][3];
        float V = redV[t][0] + redV[t][1] + redV[t][2] + redV[t][3];
        Sp[(i0 + t) * 2 + h] = S;
        Vp[(i0 + t) * 2 + h] = V;
    }
}

// Kernel 3: combine j-half partials, loss = -(1/B) * sum_i (S_i/B - log V_i)
__global__ __launch_bounds__(512) void final_kernel(
        const float* __restrict__ Sp, const float* __restrict__ Vp,
        float* __restrict__ out) {
    int i = threadIdx.x;
    float S = Sp[i * 2] + Sp[i * 2 + 1];
    float V = Vp[i * 2] + Vp[i * 2 + 1];
    float t = S * (1.0f / Bq) - logf(V);
    t = waveReduceSum(t);
    __shared__ float red[8];
    int wid = i >> 6, lane = i & 63;
    if (lane == 0) red[wid] = t;
    __syncthreads();
    if (i == 0) {
        float s = 0.f;
        #pragma unroll
        for (int w = 0; w < 8; ++w) s += red[w];
        out[0] = -s / (float)Bq;
    }
}

extern "C" void kernel_launch(void* const* d_in, const int* in_sizes, int n_in,
                              void* d_out, int out_size, void* d_ws, size_t ws_size,
                              hipStream_t stream) {
    const float* feat = (const float*)d_in[0];
    float* ws = (float*)d_ws;
    float* fT = ws;                         // Dq*Bq floats
    float* Sp = fT + (size_t)Dq * Bq;       // Bq*2
    float* Vp = Sp + (size_t)Bq * 2;        // Bq*2

    prep_kernel<<<PBLK, 256, 0, stream>>>(feat, fT);
    pair_kernel<<<Bq, 256, 0, stream>>>(feat, fT, Sp, Vp);
    final_kernel<<<1, Bq, 0, stream>>>(Sp, Vp, (float*)d_out);
}